// Round 11
// baseline (87.336 us; speedup 1.0000x reference)
//
#include <hip/hip_runtime.h>
#include <hip/hip_bf16.h>

#define Bn 512
#define Ln 2048
#define Tn 16

typedef float f32x4 __attribute__((ext_vector_type(4)));
typedef short s16x4 __attribute__((ext_vector_type(4)));
typedef int   i32x2 __attribute__((ext_vector_type(2)));

#define L2E 1.4426950408889634f
#define LN2 0.6931471805599453f

#if __has_builtin(__builtin_amdgcn_mfma_f32_16x16x16bf16_1k)
#define HAVE_MFMA1K 1
#endif

__device__ __forceinline__ f32x4 mfma16(s16x4 a, s16x4 b, f32x4 c) {
#ifdef HAVE_MFMA1K
  return __builtin_amdgcn_mfma_f32_16x16x16bf16_1k(a, b, c, 0, 0, 0);
#else
  f32x4 d;
  asm volatile("v_mfma_f32_16x16x16_bf16 %0, %1, %2, %3\n\ts_nop 7\n\ts_nop 7"
               : "=&v"(d) : "v"(a), "v"(b), "v"(c));
  return d;
#endif
}

__device__ __forceinline__ int cvtpk_bf16(float a, float b) {
  int r;
  asm("v_cvt_pk_bf16_f32 %0, %1, %2" : "=v"(r) : "v"(a), "v"(b));
  return r;
}

__device__ __forceinline__ s16x4 pack_bf16(f32x4 q) {
  i32x2 t2; t2.x = cvtpk_bf16(q.x, q.y); t2.y = cvtpk_bf16(q.z, q.w);
  return __builtin_bit_cast(s16x4, t2);
}

__device__ __forceinline__ float rl0(float x) {
  return __builtin_bit_cast(float, __builtin_amdgcn_readfirstlane(__builtin_bit_cast(int, x)));
}

// Kernel 0: lengths[b] = sum(mask[b,:])  (mask is a contiguous prefix)
__global__ __launch_bounds__(256) void len_kernel(const int* __restrict__ mask,
                                                  int* __restrict__ wsLen) {
  const int lane = threadIdx.x & 63;
  const int b = (blockIdx.x << 2) + (threadIdx.x >> 6);
  const int4* mp = (const int4*)(mask + (size_t)b * Ln);
  int cnt = 0;
#pragma unroll
  for (int i = 0; i < Ln / 4 / 64; ++i) {
    int4 v = mp[i * 64 + lane];
    cnt += v.x + v.y + v.z + v.w;
  }
  for (int m = 1; m < 64; m <<= 1) cnt += __shfl_xor(cnt, m);
  if (lane == 0) wsLen[b] = cnt;
}

// One scan step. exCur holds, per lane (= j*16+row), exp(feat[tb+j][row]).
// The 4 F values this lane needs (rows r0..r0+3 at step j) come via shfl
// (DS pipe). Renorm every 2 steps (RENORM), applied deferred (APPLY).
// Invariant: stored_T * 2^lnacc == true_T; lnacc holds only APPLIED pends.
#define GBODY(j, APPLY, RENORM)                                               \
  {                                                                           \
    float F0 = __shfl(exCur, ((j) << 4) + r0 + 0);                            \
    float F1 = __shfl(exCur, ((j) << 4) + r0 + 1);                            \
    float F2 = __shfl(exCur, ((j) << 4) + r0 + 2);                            \
    float F3 = __shfl(exCur, ((j) << 4) + r0 + 3);                            \
    const f32x4 p = mfma16(afrag, bfrag, zero);                               \
    if (APPLY) { F0 *= s; F1 *= s; F2 *= s; F3 *= s; lnacc += pend; }         \
    q.x = p.x * F0; q.y = p.y * F1; q.z = p.z * F2; q.w = p.w * F3;           \
    bfrag = pack_bf16(q);                                                     \
    if (RENORM) {                                                             \
      const float c0 = fmaxf(rl0(q.x), 1e-30f);                               \
      pend = __builtin_amdgcn_logf(c0); /* log2 */                            \
      s = __builtin_amdgcn_rcpf(c0);                                          \
    }                                                                         \
  }

#define GSTEP(j, APPLY, RENORM) GBODY(j, APPLY, RENORM)
#define TSTEP(j, APPLY, RENORM)                                               \
  if (tbase + (j) < nsteps) GBODY(j, APPLY, RENORM)

// per-group feat load: lane (= s*16+row) reads feats[b][tb+s][row], clamped.
#define LOADG(dst, tb)                                                        \
  { const int tcl = min((tb) + (lane >> 4), Ln - 1);                          \
    dst = fbase[(size_t)tcl * 16 + (lane & 15)]; }

// Kernel 1: wave (b,c) computes the transfer matrix of the EQUAL-WORK span
// [c*len/NC, (c+1)*len/NC):  T = prod_t diag(exp(feat_t)) * E,  E = exp(trans)
// Depth-4 rotating prefetch: exCur (group g, exp'd), fvN1/fvN2/fvN3 (raw
// groups g+1..g+3); body loads group g+4.
__global__ __launch_bounds__(256, 8) void crf_chunk(
    const float* __restrict__ feats, const int* __restrict__ mask,
    const int* __restrict__ tgt, const float* __restrict__ trans,
    const int* __restrict__ wsLen,
    float* __restrict__ wsT, float* __restrict__ wsLn, float* __restrict__ wsGold,
    int ncs)
{
  const int lane = threadIdx.x & 63;
  const int gwid = (blockIdx.x << 2) + (threadIdx.x >> 6);
  const int b = gwid >> ncs;
  const int c = gwid & ((1 << ncs) - 1);
  const int col = lane & 15;
  const int r0 = (lane >> 4) << 2;

  // A fragment: A[m=col][k=r0+i] = exp(trans[col][r0+i])
  s16x4 afrag;
  {
    const float4 tr = *(const float4*)(trans + col * 16 + r0);
    f32x4 e;
    e.x = __builtin_amdgcn_exp2f(tr.x * L2E);
    e.y = __builtin_amdgcn_exp2f(tr.y * L2E);
    e.z = __builtin_amdgcn_exp2f(tr.z * L2E);
    e.w = __builtin_amdgcn_exp2f(tr.w * L2E);
    afrag = pack_bf16(e);
  }

  const size_t bL = (size_t)b * Ln;
  const int len = wsLen[b];
  const int t0s = (c * len) >> ncs;
  const int t1s = ((c + 1) * len) >> ncs;
  const int nsteps = t1s - t0s;   // 32..128, never 0 (len >= Ln/2)

  f32x4 q;  // B = T (identity init). B[k=r0+i][n=col]; C/D layout == B layout.
  q.x = (r0 + 0 == col) ? 1.f : 0.f;
  q.y = (r0 + 1 == col) ? 1.f : 0.f;
  q.z = (r0 + 2 == col) ? 1.f : 0.f;
  q.w = (r0 + 3 == col) ? 1.f : 0.f;
  s16x4 bfrag = pack_bf16(q);
  float lnacc = 0.f, s = 1.f, pend = 0.f;
  const f32x4 zero = {0.f, 0.f, 0.f, 0.f};

  {
    const float* fbase = feats + bL * 16;
    float exCur, fvN1, fvN2, fvN3;
    { float fv0; LOADG(fv0, t0s); exCur = __builtin_amdgcn_exp2f(fv0 * L2E); }
    LOADG(fvN1, t0s + 4);
    LOADG(fvN2, t0s + 8);
    LOADG(fvN3, t0s + 12);

    const int nfull = nsteps >> 2;
    const int tail = nsteps & 3;
    for (int g = 0; g < nfull; ++g) {
      const float exNext = __builtin_amdgcn_exp2f(fvN1 * L2E);
      fvN1 = fvN2; fvN2 = fvN3;
      LOADG(fvN3, t0s + (g + 4) * 4);
      GSTEP(0, 1, 0) GSTEP(1, 0, 1) GSTEP(2, 1, 0) GSTEP(3, 0, 1)
      exCur = exNext;
    }
    if (tail) {
      const int tbase = nfull << 2;
      TSTEP(0, 1, 0) TSTEP(1, 0, 1) TSTEP(2, 1, 0)
    }
  }

  *(f32x4*)(wsT + ((size_t)gwid * 64 + lane) * 4) = q;
  if (lane == 0) wsLn[gwid] = lnacc;

  // ---- gold-path partial over the FIXED range [c*CHrt,(c+1)*CHrt) ----
  float gs = 0.f;
  const int CHrt = Ln >> ncs;
  const int tg0 = c * CHrt;
  const int ngold = CHrt >> 6;
  for (int k2 = 0; k2 < ngold; ++k2) {
    const int t = tg0 + k2 * 64 + lane;
    if (mask[bL + t]) {
      const int cur = tgt[bL + t];
      const int prv = (t == 0) ? 0 : tgt[bL + t - 1];  // START_TAG = 0
      gs += trans[cur * 16 + prv] + feats[(bL + t) * 16 + cur];
    }
  }
  for (int m = 1; m < 64; m <<= 1) gs += __shfl_xor(gs, m);
  if (lane == 0) atomicAdd(wsGold + b, gs);
}

// Kernel 2: per-batch wave combines chunk matrices against u0 = e_START,
// terminal logsumexp with trans[STOP] row, subtracts gold, reduces to scalar.
__global__ __launch_bounds__(256) void crf_combine(
    const int* __restrict__ tgt, const float* __restrict__ trans,
    const int* __restrict__ wsLen, const float* __restrict__ wsT,
    const float* __restrict__ wsLn, const float* __restrict__ wsGold,
    float* __restrict__ out, int ncs)
{
  const int lane = threadIdx.x & 63;
  const int b = (blockIdx.x << 2) + (threadIdx.x >> 6);
  const int col = lane & 15;
  const int NCrt = 1 << ncs;

  float u = (col == 0) ? 1.f : 0.f;  // exp(fv_init) = e_START
  float Lacc = 0.f;                  // log2 units

  for (int c = 0; c < NCrt; ++c) {
    const float4 tf = *(const float4*)(wsT + (((size_t)(b << ncs) + c) * 64 + lane) * 4);
    float p0 = tf.x * u, p1 = tf.y * u, p2 = tf.z * u, p3 = tf.w * u;
    for (int m = 1; m < 16; m <<= 1) {
      p0 += __shfl_xor(p0, m); p1 += __shfl_xor(p1, m);
      p2 += __shfl_xor(p2, m); p3 += __shfl_xor(p3, m);
    }
    const float pre = (lane & 2) ? ((lane & 1) ? p3 : p2) : ((lane & 1) ? p1 : p0);
    const int srcl = ((lane & 12) << 2) + (lane & 3);
    float un = __shfl(pre, srcl);
    const float c0 = fmaxf(rl0(un), 1e-30f);
    Lacc += __builtin_amdgcn_logf(c0) + wsLn[(size_t)(b << ncs) + c];
    u = un * __builtin_amdgcn_rcpf(c0);
  }

  float v = u * __builtin_amdgcn_exp2f(trans[16 + col] * L2E);  // STOP_TAG = 1
  for (int m = 1; m < 16; m <<= 1) v += __shfl_xor(v, m);
  v = fmaxf(v, 1e-30f);
  const float fwd = LN2 * (Lacc + __builtin_amdgcn_logf(v));

  if (lane == 0) {
    const size_t bL = (size_t)b * Ln;
    const int len = wsLen[b];
    const int last = tgt[bL + len - 1];
    const float gold = wsGold[b] + trans[16 + last];
    atomicAdd(out, (fwd - gold) * (1.f / 512.f));
  }
}

extern "C" void kernel_launch(void* const* d_in, const int* in_sizes, int n_in,
                              void* d_out, int out_size, void* d_ws, size_t ws_size,
                              hipStream_t stream) {
  const float* feats = (const float*)d_in[0];
  const int* mask = (const int*)d_in[1];
  const int* tgt = (const int*)d_in[2];
  const float* trans = (const float*)d_in[3];
  float* out = (float*)d_out;

  char* ws = (char*)d_ws;
  int*   wsLen  = (int*)ws;                        // 512 * 4B
  float* wsGold = (float*)(ws + 2048);             // 512 * 4B
  float* wsLn   = (float*)(ws + 4096);             // up to 32*512*4B = 64KB
  float* wsT    = (float*)(ws + 4096 + 65536);     // (1<<ncs)*512*1KB

  const size_t base = 4096 + 65536;
  int ncs = 3;
  if (ws_size >= base + ((size_t)32 * Bn * 256 * 4)) ncs = 5;       // ~16.8 MB
  else if (ws_size >= base + ((size_t)16 * Bn * 256 * 4)) ncs = 4;  // ~8.5 MB

  const int nwaves = Bn << ncs;

  hipMemsetAsync(d_out, 0, sizeof(float), stream);
  hipMemsetAsync(wsGold, 0, Bn * sizeof(float), stream);

  len_kernel<<<Bn / 4, 256, 0, stream>>>(mask, wsLen);
  crf_chunk<<<nwaves / 4, 256, 0, stream>>>(feats, mask, tgt, trans, wsLen,
                                            wsT, wsLn, wsGold, ncs);
  crf_combine<<<Bn / 4, 256, 0, stream>>>(tgt, trans, wsLen, wsT, wsLn, wsGold, out, ncs);
}

// Round 15
// 74.337 us; speedup vs baseline: 1.1749x; 1.1749x over previous
//
#include <hip/hip_runtime.h>
#include <hip/hip_bf16.h>

#define Bn 512
#define Ln 2048
#define Tn 16

typedef float f32x4 __attribute__((ext_vector_type(4)));
typedef short s16x4 __attribute__((ext_vector_type(4)));
typedef int   i32x2 __attribute__((ext_vector_type(2)));

#define L2E 1.4426950408889634f
#define LN2 0.6931471805599453f

#if __has_builtin(__builtin_amdgcn_mfma_f32_16x16x16bf16_1k)
#define HAVE_MFMA1K 1
#endif

__device__ __forceinline__ f32x4 mfma16(s16x4 a, s16x4 b, f32x4 c) {
#ifdef HAVE_MFMA1K
  return __builtin_amdgcn_mfma_f32_16x16x16bf16_1k(a, b, c, 0, 0, 0);
#else
  f32x4 d;
  asm volatile("v_mfma_f32_16x16x16_bf16 %0, %1, %2, %3\n\ts_nop 7\n\ts_nop 7"
               : "=&v"(d) : "v"(a), "v"(b), "v"(c));
  return d;
#endif
}

__device__ __forceinline__ int cvtpk_bf16(float a, float b) {
  int r;
  asm("v_cvt_pk_bf16_f32 %0, %1, %2" : "=v"(r) : "v"(a), "v"(b));
  return r;
}

__device__ __forceinline__ s16x4 pack_bf16(f32x4 q) {
  i32x2 t2; t2.x = cvtpk_bf16(q.x, q.y); t2.y = cvtpk_bf16(q.z, q.w);
  return __builtin_bit_cast(s16x4, t2);
}

__device__ __forceinline__ float rl0(float x) {
  return __builtin_bit_cast(float, __builtin_amdgcn_readfirstlane(__builtin_bit_cast(int, x)));
}

// Kernel 0: lengths[b] = sum(mask[b,:])  (mask is a contiguous prefix)
__global__ __launch_bounds__(256) void len_kernel(const int* __restrict__ mask,
                                                  int* __restrict__ wsLen) {
  const int lane = threadIdx.x & 63;
  const int b = (blockIdx.x << 2) + (threadIdx.x >> 6);
  const int4* mp = (const int4*)(mask + (size_t)b * Ln);
  int cnt = 0;
#pragma unroll
  for (int i = 0; i < Ln / 4 / 64; ++i) {
    int4 v = mp[i * 64 + lane];
    cnt += v.x + v.y + v.z + v.w;
  }
  for (int m = 1; m < 64; m <<= 1) cnt += __shfl_xor(cnt, m);
  if (lane == 0) wsLen[b] = cnt;
}

// One scan step. exCur holds, per lane (= j*16+row), exp(feat[tb+j][row]).
// The 4 F values this lane needs come via shfl (DS pipe). Renorm every 2
// steps (RENORM), applied deferred (APPLY).
// Invariant: stored_T * 2^lnacc == true_T; lnacc holds only APPLIED pends.
#define GBODY(j, APPLY, RENORM)                                               \
  {                                                                           \
    float F0 = __shfl(exCur, ((j) << 4) + r0 + 0);                            \
    float F1 = __shfl(exCur, ((j) << 4) + r0 + 1);                            \
    float F2 = __shfl(exCur, ((j) << 4) + r0 + 2);                            \
    float F3 = __shfl(exCur, ((j) << 4) + r0 + 3);                            \
    const f32x4 p = mfma16(afrag, bfrag, zero);                               \
    if (APPLY) { F0 *= s; F1 *= s; F2 *= s; F3 *= s; lnacc += pend; }         \
    q.x = p.x * F0; q.y = p.y * F1; q.z = p.z * F2; q.w = p.w * F3;           \
    bfrag = pack_bf16(q);                                                     \
    if (RENORM) {                                                             \
      const float c0 = fmaxf(rl0(q.x), 1e-30f);                               \
      pend = __builtin_amdgcn_logf(c0); /* log2 */                            \
      s = __builtin_amdgcn_rcpf(c0);                                          \
    }                                                                         \
  }

#define GSTEP(j, APPLY, RENORM) GBODY(j, APPLY, RENORM)
#define TSTEP(j, APPLY, RENORM)                                               \
  if (tbase + (j) < nsteps) GBODY(j, APPLY, RENORM)

// per-group feat load: lane (= s*16+row) reads feats[b][tb+s][row], clamped.
#define LOADG(dst, tb)                                                        \
  { const int tcl = min((tb) + (lane >> 4), Ln - 1);                          \
    dst = fbase[(size_t)tcl * 16 + (lane & 15)]; }

// Kernel 1: wave (b,c) computes the transfer matrix of the EQUAL-WORK span
// [c*len/NC, (c+1)*len/NC):  T = prod_t diag(exp(feat_t)) * E,  E = exp(trans)
// Depth-4 rotating prefetch: exCur (group g, exp'd), fvN1/fvN2/fvN3 (raw
// groups g+1..g+3); body loads group g+4.
__global__ __launch_bounds__(256, 8) void crf_chunk(
    const float* __restrict__ feats, const int* __restrict__ mask,
    const int* __restrict__ tgt, const float* __restrict__ trans,
    const int* __restrict__ wsLen,
    float* __restrict__ wsT, float* __restrict__ wsLn, float* __restrict__ wsGold,
    int ncs)
{
  const int lane = threadIdx.x & 63;
  const int gwid = (blockIdx.x << 2) + (threadIdx.x >> 6);
  const int b = gwid >> ncs;
  const int c = gwid & ((1 << ncs) - 1);
  const int col = lane & 15;
  const int r0 = (lane >> 4) << 2;

  // A fragment: A[m=col][k=r0+i] = exp(trans[col][r0+i])
  s16x4 afrag;
  {
    const float4 tr = *(const float4*)(trans + col * 16 + r0);
    f32x4 e;
    e.x = __builtin_amdgcn_exp2f(tr.x * L2E);
    e.y = __builtin_amdgcn_exp2f(tr.y * L2E);
    e.z = __builtin_amdgcn_exp2f(tr.z * L2E);
    e.w = __builtin_amdgcn_exp2f(tr.w * L2E);
    afrag = pack_bf16(e);
  }

  const size_t bL = (size_t)b * Ln;
  const int len = wsLen[b];
  const int t0s = (c * len) >> ncs;
  const int t1s = ((c + 1) * len) >> ncs;
  const int nsteps = t1s - t0s;   // 64..128 at ncs=4, never 0 (len >= Ln/2)

  f32x4 q;  // B = T (identity init). B[k=r0+i][n=col]; C/D layout == B layout.
  q.x = (r0 + 0 == col) ? 1.f : 0.f;
  q.y = (r0 + 1 == col) ? 1.f : 0.f;
  q.z = (r0 + 2 == col) ? 1.f : 0.f;
  q.w = (r0 + 3 == col) ? 1.f : 0.f;
  s16x4 bfrag = pack_bf16(q);
  float lnacc = 0.f, s = 1.f, pend = 0.f;
  const f32x4 zero = {0.f, 0.f, 0.f, 0.f};

  {
    const float* fbase = feats + bL * 16;
    float exCur, fvN1, fvN2, fvN3;
    { float fv0; LOADG(fv0, t0s); exCur = __builtin_amdgcn_exp2f(fv0 * L2E); }
    LOADG(fvN1, t0s + 4);
    LOADG(fvN2, t0s + 8);
    LOADG(fvN3, t0s + 12);

    const int nfull = nsteps >> 2;
    const int tail = nsteps & 3;
    for (int g = 0; g < nfull; ++g) {
      const float exNext = __builtin_amdgcn_exp2f(fvN1 * L2E);
      fvN1 = fvN2; fvN2 = fvN3;
      LOADG(fvN3, t0s + (g + 4) * 4);
      GSTEP(0, 1, 0) GSTEP(1, 0, 1) GSTEP(2, 1, 0) GSTEP(3, 0, 1)
      exCur = exNext;
    }
    if (tail) {
      const int tbase = nfull << 2;
      TSTEP(0, 1, 0) TSTEP(1, 0, 1) TSTEP(2, 1, 0)
    }
  }

  *(f32x4*)(wsT + ((size_t)gwid * 64 + lane) * 4) = q;
  if (lane == 0) wsLn[gwid] = lnacc;

  // ---- gold-path partial over the FIXED range [c*CHrt,(c+1)*CHrt) ----
  float gs = 0.f;
  const int CHrt = Ln >> ncs;
  const int tg0 = c * CHrt;
  const int ngold = CHrt >> 6;
  for (int k2 = 0; k2 < ngold; ++k2) {
    const int t = tg0 + k2 * 64 + lane;
    if (mask[bL + t]) {
      const int cur = tgt[bL + t];
      const int prv = (t == 0) ? 0 : tgt[bL + t - 1];  // START_TAG = 0
      gs += trans[cur * 16 + prv] + feats[(bL + t) * 16 + cur];
    }
  }
  for (int m = 1; m < 64; m <<= 1) gs += __shfl_xor(gs, m);
  if (lane == 0) atomicAdd(wsGold + b, gs);
}

// Kernel 2: per-batch wave combines chunk matrices against u0 = e_START,
// terminal logsumexp with trans[STOP] row, subtracts gold, reduces to scalar.
__global__ __launch_bounds__(256) void crf_combine(
    const int* __restrict__ tgt, const float* __restrict__ trans,
    const int* __restrict__ wsLen, const float* __restrict__ wsT,
    const float* __restrict__ wsLn, const float* __restrict__ wsGold,
    float* __restrict__ out, int ncs)
{
  const int lane = threadIdx.x & 63;
  const int b = (blockIdx.x << 2) + (threadIdx.x >> 6);
  const int col = lane & 15;
  const int NCrt = 1 << ncs;

  float u = (col == 0) ? 1.f : 0.f;  // exp(fv_init) = e_START
  float Lacc = 0.f;                  // log2 units

  for (int c = 0; c < NCrt; ++c) {
    const float4 tf = *(const float4*)(wsT + (((size_t)(b << ncs) + c) * 64 + lane) * 4);
    float p0 = tf.x * u, p1 = tf.y * u, p2 = tf.z * u, p3 = tf.w * u;
    for (int m = 1; m < 16; m <<= 1) {
      p0 += __shfl_xor(p0, m); p1 += __shfl_xor(p1, m);
      p2 += __shfl_xor(p2, m); p3 += __shfl_xor(p3, m);
    }
    const float pre = (lane & 2) ? ((lane & 1) ? p3 : p2) : ((lane & 1) ? p1 : p0);
    const int srcl = ((lane & 12) << 2) + (lane & 3);
    float un = __shfl(pre, srcl);
    const float c0 = fmaxf(rl0(un), 1e-30f);
    Lacc += __builtin_amdgcn_logf(c0) + wsLn[(size_t)(b << ncs) + c];
    u = un * __builtin_amdgcn_rcpf(c0);
  }

  float v = u * __builtin_amdgcn_exp2f(trans[16 + col] * L2E);  // STOP_TAG = 1
  for (int m = 1; m < 16; m <<= 1) v += __shfl_xor(v, m);
  v = fmaxf(v, 1e-30f);
  const float fwd = LN2 * (Lacc + __builtin_amdgcn_logf(v));

  if (lane == 0) {
    const size_t bL = (size_t)b * Ln;
    const int len = wsLen[b];
    const int last = tgt[bL + len - 1];
    const float gold = wsGold[b] + trans[16 + last];
    atomicAdd(out, (fwd - gold) * (1.f / 512.f));
  }
}

extern "C" void kernel_launch(void* const* d_in, const int* in_sizes, int n_in,
                              void* d_out, int out_size, void* d_ws, size_t ws_size,
                              hipStream_t stream) {
  const float* feats = (const float*)d_in[0];
  const int* mask = (const int*)d_in[1];
  const int* tgt = (const int*)d_in[2];
  const float* trans = (const float*)d_in[3];
  float* out = (float*)d_out;

  char* ws = (char*)d_ws;
  int*   wsLen  = (int*)ws;                        // 512 * 4B
  float* wsGold = (float*)(ws + 2048);             // 512 * 4B
  float* wsLn   = (float*)(ws + 4096);             // up to 16*512*4B = 32KB
  float* wsT    = (float*)(ws + 4096 + 65536);     // (1<<ncs)*512*1KB

  const size_t base = 4096 + 65536;
  int ncs = 3;
  if (ws_size >= base + ((size_t)16 * Bn * 256 * 4)) ncs = 4;  // ~8.5 MB

  const int nwaves = Bn << ncs;

  hipMemsetAsync(d_out, 0, sizeof(float), stream);
  hipMemsetAsync(wsGold, 0, Bn * sizeof(float), stream);

  len_kernel<<<Bn / 4, 256, 0, stream>>>(mask, wsLen);
  crf_chunk<<<nwaves / 4, 256, 0, stream>>>(feats, mask, tgt, trans, wsLen,
                                            wsT, wsLn, wsGold, ncs);
  crf_combine<<<Bn / 4, 256, 0, stream>>>(tgt, trans, wsLen, wsT, wsLn, wsGold, out, ncs);
}